// Round 7
// baseline (233.647 us; speedup 1.0000x reference)
//
#include <hip/hip_runtime.h>

// ---------------------------------------------------------------------------
// MultiHeadAttention: B=2, T=2048, C=1024, H=16, D=64
// cast x -> bf16 ; transpose W_qkv, W_out -> bf16 [N][K] ;
// QKV GEMM (glds dbuf, 64x128 tile, 6/CU) -> Q (prescaled), K, V [b,h,t,d] ;
// vtrans -> V^T ; flash attention SPLIT-K x2 (fixed-base softmax), Q in regs,
// K/V glds dbuf XOR-swizzled, l via MFMA ones-trick ;
// out GEMM 64x64 tile 4/CU with FUSED combine ((P0+P1)*rcp(l0+l1) applied in
// A-staging) + bias -> fp32.
// ---------------------------------------------------------------------------

typedef float  f32x4  __attribute__((ext_vector_type(4)));
typedef __bf16 bf16x8 __attribute__((ext_vector_type(8)));
typedef __bf16 bf16x4 __attribute__((ext_vector_type(4)));
typedef short  s16x4  __attribute__((ext_vector_type(4)));

#define QSCALE 0.18033688011112042f   // 0.125 * log2(e)

static __device__ __forceinline__ f32x4 mfma32(bf16x8 a, bf16x8 b, f32x4 c) {
    return __builtin_amdgcn_mfma_f32_16x16x32_bf16(a, b, c, 0, 0, 0);
}

static __device__ __forceinline__ f32x4 mfma16(bf16x4 a, bf16x4 b, f32x4 c) {
#if __has_builtin(__builtin_amdgcn_mfma_f32_16x16x16bf16_1k)
    return __builtin_amdgcn_mfma_f32_16x16x16bf16_1k(
        __builtin_bit_cast(s16x4, a), __builtin_bit_cast(s16x4, b), c, 0, 0, 0);
#else
    bf16x8 a8, b8;
    a8[0] = a[0]; a8[1] = a[1]; a8[2] = a[2]; a8[3] = a[3];
    a8[4] = a[0]; a8[5] = a[1]; a8[6] = a[2]; a8[7] = a[3];
    b8[0] = b[0]; b8[1] = b[1]; b8[2] = b[2]; b8[3] = b[3];
    b8[4] = __bf16(0.0f); b8[5] = __bf16(0.0f);
    b8[6] = __bf16(0.0f); b8[7] = __bf16(0.0f);
    return __builtin_amdgcn_mfma_f32_16x16x32_bf16(a8, b8, c, 0, 0, 0);
#endif
}

static __device__ __forceinline__ bf16x8 ld8(const unsigned short* p) {
    return __builtin_bit_cast(bf16x8, *(const uint4*)p);
}
static __device__ __forceinline__ bf16x4 ld4(const unsigned short* p) {
    return __builtin_bit_cast(bf16x4, *(const uint2*)p);
}
static __device__ __forceinline__ unsigned short bfbits(float f) {
    __bf16 h = (__bf16)f;
    return __builtin_bit_cast(unsigned short, h);
}
static __device__ __forceinline__ float bf2f(unsigned short u) {
    unsigned int v = ((unsigned int)u) << 16;
    return __builtin_bit_cast(float, v);
}
static __device__ __forceinline__ float frcp(float x) {
#if __has_builtin(__builtin_amdgcn_rcpf)
    return __builtin_amdgcn_rcpf(x);
#else
    return 1.0f / x;
#endif
}

static __device__ __forceinline__ void glds16(const unsigned short* g,
                                              unsigned short* lds_base) {
    __builtin_amdgcn_global_load_lds(
        (const __attribute__((address_space(1))) unsigned int*)g,
        (__attribute__((address_space(3))) unsigned int*)lds_base, 16, 0, 0);
}

// ---------------------------------------------------------------- cast x
__global__ __launch_bounds__(256) void cast_x_kernel(
    const float* __restrict__ x, unsigned short* __restrict__ xb) {
    int i = blockIdx.x * 256 + threadIdx.x;
    float4 v = ((const float4*)x)[i];
    ushort4 o;
    o.x = bfbits(v.x); o.y = bfbits(v.y); o.z = bfbits(v.z); o.w = bfbits(v.w);
    ((ushort4*)xb)[i] = o;
}

// ------------------------------------------------- transpose + cast weights
__global__ __launch_bounds__(256) void transpose_cast_kernel(
    const float* __restrict__ W, unsigned short* __restrict__ Wt, int K, int N) {
    __shared__ float tile[32][33];
    int tx = threadIdx.x & 31, ty = threadIdx.x >> 5;
    int n0 = blockIdx.x * 32, k0 = blockIdx.y * 32;
#pragma unroll
    for (int i = 0; i < 4; i++) {
        int r = ty + i * 8;
        tile[r][tx] = W[(size_t)(k0 + r) * N + n0 + tx];
    }
    __syncthreads();
#pragma unroll
    for (int i = 0; i < 4; i++) {
        int r = ty + i * 8;
        Wt[(size_t)(n0 + r) * K + k0 + tx] = bfbits(tile[tx][r]);
    }
}

// ---------------------------------------------------------------- QKV GEMM
// 64x128 tile, grid 24x64 = 1536 blocks (~5-6/CU) for latency overlap.
__global__ __launch_bounds__(256, 5) void qkv_gemm_kernel(
    const unsigned short* __restrict__ A, const unsigned short* __restrict__ Bt,
    const float* __restrict__ bias, unsigned short* __restrict__ Qb,
    unsigned short* __restrict__ Kb, unsigned short* __restrict__ Vb) {
    __shared__ unsigned short As[2][64 * 32];
    __shared__ unsigned short Bs[2][128 * 32];
    const int tid = threadIdx.x;
    const int lane = tid & 63, w = tid >> 6;
    const int ln = lane & 15, quad = lane >> 4;
    const int wm = (w >> 1) * 32, wn = (w & 1) * 64;
    const int m0 = blockIdx.y * 64, n0 = blockIdx.x * 128;
    const int sr = lane >> 2, sc = (lane & 3) * 8;
    f32x4 acc[2][4] = {};
    {
        int ra = w * 16;
        glds16(&A[(size_t)(m0 + ra + sr) * 1024 + sc], &As[0][ra * 32]);
#pragma unroll
        for (int i = 0; i < 2; i++) {
            int r0 = w * 32 + i * 16;
            glds16(&Bt[(size_t)(n0 + r0 + sr) * 1024 + sc], &Bs[0][r0 * 32]);
        }
    }
    __syncthreads();
    for (int kt = 0; kt < 32; kt++) {
        const int cur = kt & 1;
        if (kt + 1 < 32) {
            const int nxt = cur ^ 1;
            const int kc = (kt + 1) * 32;
            int ra = w * 16;
            glds16(&A[(size_t)(m0 + ra + sr) * 1024 + kc + sc], &As[nxt][ra * 32]);
#pragma unroll
            for (int i = 0; i < 2; i++) {
                int r0 = w * 32 + i * 16;
                glds16(&Bt[(size_t)(n0 + r0 + sr) * 1024 + kc + sc], &Bs[nxt][r0 * 32]);
            }
        }
        bf16x8 af[2], bf[4];
#pragma unroll
        for (int mi = 0; mi < 2; mi++)
            af[mi] = ld8(&As[cur][(wm + mi * 16 + ln) * 32 + quad * 8]);
#pragma unroll
        for (int ni = 0; ni < 4; ni++)
            bf[ni] = ld8(&Bs[cur][(wn + ni * 16 + ln) * 32 + quad * 8]);
#pragma unroll
        for (int mi = 0; mi < 2; mi++)
#pragma unroll
            for (int ni = 0; ni < 4; ni++)
                acc[mi][ni] = mfma32(af[mi], bf[ni], acc[mi][ni]);
        __syncthreads();
    }
#pragma unroll
    for (int mi = 0; mi < 2; mi++)
#pragma unroll
        for (int ni = 0; ni < 4; ni++) {
            int gn = n0 + wn + ni * 16 + ln;
            float bi = bias[gn];
            int h = gn / 192, rr = gn - h * 192;
#pragma unroll
            for (int r = 0; r < 4; r++) {
                int gm = m0 + wm + mi * 16 + quad * 4 + r;
                float v = acc[mi][ni][r] + bi;
                int b = gm >> 11, t = gm & 2047;
                size_t base = ((size_t)(b * 16 + h) * 2048 + t) * 64;
                if (rr < 64)        Qb[base + rr] = bfbits(v * QSCALE);
                else if (rr < 128)  Kb[base + rr - 64] = bfbits(v);
                else                Vb[base + rr - 128] = bfbits(v);
            }
        }
}

// ---------------------------------------------------------------- V^T
__global__ __launch_bounds__(256) void vtrans_kernel(
    const unsigned short* __restrict__ Vb, unsigned short* __restrict__ Vt) {
    __shared__ unsigned short tile[64][72];
    const int bh = blockIdx.y, t0 = blockIdx.x * 64;
    const unsigned short* src = Vb + ((size_t)bh * 2048 + t0) * 64;
    const int tid = threadIdx.x;
#pragma unroll
    for (int i = 0; i < 2; i++) {
        int f = (tid + i * 256) * 8;
        int r = f >> 6, c = f & 63;
        *(uint4*)&tile[r][c] = *(const uint4*)&src[f];
    }
    __syncthreads();
    int d = tid >> 2, seg = (tid & 3) * 16;
    unsigned short tmp[16];
#pragma unroll
    for (int j = 0; j < 16; j++) tmp[j] = tile[seg + j][d];
    unsigned short* dst = Vt + ((size_t)bh * 64 + d) * 2048 + t0 + seg;
    *(uint4*)&dst[0] = *(uint4*)&tmp[0];
    *(uint4*)&dst[8] = *(uint4*)&tmp[8];
}

// ---------------------------------------------------------------- attention
__global__ __launch_bounds__(256, 4) void attn_kernel(
    const unsigned short* __restrict__ Q, const unsigned short* __restrict__ K,
    const unsigned short* __restrict__ Vt, unsigned short* __restrict__ Op0,
    unsigned short* __restrict__ Op1, float* __restrict__ Lpart) {
    __shared__ unsigned short Ks[2][64 * 64];
    __shared__ unsigned short Vs[2][64 * 64];
    const int bh = blockIdx.y, qt = blockIdx.x, ks = blockIdx.z;
    const unsigned short* Qg = Q + ((size_t)bh * 2048 + qt * 128) * 64;
    const unsigned short* Kg = K + ((size_t)bh * 2048 + ks * 1024) * 64;
    const unsigned short* Vg = Vt + (size_t)bh * 64 * 2048 + ks * 1024;
    const int tid = threadIdx.x;
    const int lane = tid & 63, w = tid >> 6;
    const int ln = lane & 15, quad = lane >> 4;
    const int lr = lane >> 3, lg = lane & 7;

    bf16x8 qf[2][2];
#pragma unroll
    for (int h = 0; h < 2; h++) {
        const unsigned short* qp = Qg + (size_t)(w * 32 + h * 16 + ln) * 64;
        qf[h][0] = ld8(qp + quad * 8);
        qf[h][1] = ld8(qp + 32 + quad * 8);
    }
#pragma unroll
    for (int i = 0; i < 2; i++) {
        int r0 = w * 16 + i * 8;
        int r = r0 + lr;
        int g = lg ^ (r & 7);
        glds16(Kg + (size_t)r * 64 + g * 8, &Ks[0][r0 * 64]);
        glds16(Vg + (size_t)r * 2048 + g * 8, &Vs[0][r0 * 64]);
    }
    __syncthreads();

    bf16x4 ones;
    ones[0] = __bf16(1.0f); ones[1] = __bf16(1.0f);
    ones[2] = __bf16(1.0f); ones[3] = __bf16(1.0f);
    f32x4 o[2][4] = {};
    f32x4 lacc[2] = {};

    for (int kt = 0; kt < 16; kt++) {
        const int cur = kt & 1;
        if (kt + 1 < 16) {
            const int nxt = cur ^ 1;
            const unsigned short* Kgt = Kg + (size_t)(kt + 1) * 64 * 64;
            const unsigned short* Vgt = Vg + (size_t)(kt + 1) * 64;
#pragma unroll
            for (int i = 0; i < 2; i++) {
                int r0 = w * 16 + i * 8;
                int r = r0 + lr;
                int g = lg ^ (r & 7);
                glds16(Kgt + (size_t)r * 64 + g * 8, &Ks[nxt][r0 * 64]);
                glds16(Vgt + (size_t)r * 2048 + g * 8, &Vs[nxt][r0 * 64]);
            }
        }
        f32x4 s[2][4] = {};
#pragma unroll
        for (int ms = 0; ms < 4; ms++) {
            int r = ms * 16 + ln;
            bf16x8 a0 = ld8(&Ks[cur][r * 64 + ((quad) ^ (r & 7)) * 8]);
            bf16x8 a1 = ld8(&Ks[cur][r * 64 + ((4 + quad) ^ (r & 7)) * 8]);
#pragma unroll
            for (int h = 0; h < 2; h++) {
                s[h][ms] = mfma32(a0, qf[h][0], s[h][ms]);
                s[h][ms] = mfma32(a1, qf[h][1], s[h][ms]);
            }
        }
        bf16x4 pb[2][4];
#pragma unroll
        for (int h = 0; h < 2; h++)
#pragma unroll
            for (int ms = 0; ms < 4; ms++)
#pragma unroll
                for (int r = 0; r < 4; r++)
                    pb[h][ms][r] = (__bf16)exp2f(s[h][ms][r]);
#pragma unroll
        for (int h = 0; h < 2; h++)
#pragma unroll
            for (int ms = 0; ms < 4; ms++)
                lacc[h] = mfma16(ones, pb[h][ms], lacc[h]);
#pragma unroll
        for (int df = 0; df < 4; df++) {
            int r = df * 16 + ln;
#pragma unroll
            for (int ms = 0; ms < 4; ms++) {
                int c = ms * 4 + quad;
                bf16x4 a = ld4(&Vs[cur][r * 64 + (((c >> 1) ^ (r & 7)) * 8) + (c & 1) * 4]);
                o[0][df] = mfma16(a, pb[0][ms], o[0][df]);
                o[1][df] = mfma16(a, pb[1][ms], o[1][df]);
            }
        }
        __syncthreads();
    }
    const int b = bh >> 4, hh = bh & 15;
    unsigned short* Ob = ks ? Op1 : Op0;
#pragma unroll
    for (int h = 0; h < 2; h++) {
        int qrow = qt * 128 + w * 32 + h * 16 + ln;
        if (quad == 0)
            Lpart[(size_t)ks * 65536 + bh * 2048 + qrow] = lacc[h][0];
        size_t row = ((size_t)b * 2048 + qrow) * 1024 + hh * 64;
#pragma unroll
        for (int df = 0; df < 4; df++) {
            ushort4 pk;
            pk.x = bfbits(o[h][df][0]); pk.y = bfbits(o[h][df][1]);
            pk.z = bfbits(o[h][df][2]); pk.w = bfbits(o[h][df][3]);
            *(ushort4*)&Ob[row + df * 16 + quad * 4] = pk;
        }
    }
}

// ------------------------------------------- out GEMM with fused combine
// 64x64 tile, grid 16x64 = 1024 blocks (4/CU). A-stage computes
// (P0+P1) * rcp(l0+l1) in VGPRs -> ds_write_b128; B via glds dbuf.
__global__ __launch_bounds__(256, 4) void out_gemm_kernel(
    const unsigned short* __restrict__ P0, const unsigned short* __restrict__ P1,
    const float* __restrict__ L, const unsigned short* __restrict__ Bt,
    const float* __restrict__ bias, float* __restrict__ out) {
    __shared__ unsigned short As[2][64 * 32];
    __shared__ unsigned short Bs[2][64 * 32];
    const int tid = threadIdx.x;
    const int lane = tid & 63, w = tid >> 6;
    const int ln = lane & 15, quad = lane >> 4;
    const int wm = (w >> 1) * 32, wn = (w & 1) * 32;
    const int m0 = blockIdx.y * 64, n0 = blockIdx.x * 64;
    const int sr = tid >> 2, sc = (tid & 3) * 8;       // A-stage: 64 rows x 32
    const int br = lane >> 2, bc = (lane & 3) * 8;     // B-stage per wave: 16 rows
    f32x4 acc[2][2] = {};

    // A-stage helper values for row m0+sr
    const int gm = m0 + sr, bb = gm >> 11, tt = gm & 2047;
    const size_t arow = (size_t)gm * 1024;

    // prologue: stage tile 0
    {
        int c0 = sc;                                   // k-offset 0
        int h = c0 >> 6;
        float inv = frcp(L[(bb * 16 + h) * 2048 + tt] + L[65536 + (bb * 16 + h) * 2048 + tt]);
        ushort4 a0 = *(const ushort4*)&P0[arow + c0];
        ushort4 a1 = *(const ushort4*)&P0[arow + c0 + 4];
        ushort4 c0v = *(const ushort4*)&P1[arow + c0];
        ushort4 c1v = *(const ushort4*)&P1[arow + c0 + 4];
        unsigned short r8[8];
        r8[0] = bfbits((bf2f(a0.x) + bf2f(c0v.x)) * inv);
        r8[1] = bfbits((bf2f(a0.y) + bf2f(c0v.y)) * inv);
        r8[2] = bfbits((bf2f(a0.z) + bf2f(c0v.z)) * inv);
        r8[3] = bfbits((bf2f(a0.w) + bf2f(c0v.w)) * inv);
        r8[4] = bfbits((bf2f(a1.x) + bf2f(c1v.x)) * inv);
        r8[5] = bfbits((bf2f(a1.y) + bf2f(c1v.y)) * inv);
        r8[6] = bfbits((bf2f(a1.z) + bf2f(c1v.z)) * inv);
        r8[7] = bfbits((bf2f(a1.w) + bf2f(c1v.w)) * inv);
        *(uint4*)&As[0][sr * 32 + sc] = *(uint4*)r8;
        glds16(&Bt[(size_t)(n0 + w * 16 + br) * 1024 + bc], &Bs[0][(w * 16) * 32]);
    }
    __syncthreads();
    for (int kt = 0; kt < 32; kt++) {
        const int cur = kt & 1;
        ushort4 a0, a1, c0v, c1v;
        float inv;
        if (kt + 1 < 32) {
            const int nxt = cur ^ 1;
            const int kc = (kt + 1) * 32;
            glds16(&Bt[(size_t)(n0 + w * 16 + br) * 1024 + kc + bc], &Bs[nxt][(w * 16) * 32]);
            int c0 = kc + sc;
            int h = c0 >> 6;
            inv = frcp(L[(bb * 16 + h) * 2048 + tt] + L[65536 + (bb * 16 + h) * 2048 + tt]);
            a0 = *(const ushort4*)&P0[arow + c0];
            a1 = *(const ushort4*)&P0[arow + c0 + 4];
            c0v = *(const ushort4*)&P1[arow + c0];
            c1v = *(const ushort4*)&P1[arow + c0 + 4];
        }
        bf16x8 af[2], bf[2];
#pragma unroll
        for (int mi = 0; mi < 2; mi++)
            af[mi] = ld8(&As[cur][(wm + mi * 16 + ln) * 32 + quad * 8]);
#pragma unroll
        for (int ni = 0; ni < 2; ni++)
            bf[ni] = ld8(&Bs[cur][(wn + ni * 16 + ln) * 32 + quad * 8]);
#pragma unroll
        for (int mi = 0; mi < 2; mi++)
#pragma unroll
            for (int ni = 0; ni < 2; ni++)
                acc[mi][ni] = mfma32(af[mi], bf[ni], acc[mi][ni]);
        if (kt + 1 < 32) {
            const int nxt = cur ^ 1;
            unsigned short r8[8];
            r8[0] = bfbits((bf2f(a0.x) + bf2f(c0v.x)) * inv);
            r8[1] = bfbits((bf2f(a0.y) + bf2f(c0v.y)) * inv);
            r8[2] = bfbits((bf2f(a0.z) + bf2f(c0v.z)) * inv);
            r8[3] = bfbits((bf2f(a0.w) + bf2f(c0v.w)) * inv);
            r8[4] = bfbits((bf2f(a1.x) + bf2f(c1v.x)) * inv);
            r8[5] = bfbits((bf2f(a1.y) + bf2f(c1v.y)) * inv);
            r8[6] = bfbits((bf2f(a1.z) + bf2f(c1v.z)) * inv);
            r8[7] = bfbits((bf2f(a1.w) + bf2f(c1v.w)) * inv);
            *(uint4*)&As[nxt][sr * 32 + sc] = *(uint4*)r8;
        }
        __syncthreads();
    }
#pragma unroll
    for (int mi = 0; mi < 2; mi++)
#pragma unroll
        for (int ni = 0; ni < 2; ni++) {
            int gn = n0 + wn + ni * 16 + ln;
            float bi = bias[gn];
#pragma unroll
            for (int r = 0; r < 4; r++) {
                int gmm = m0 + wm + mi * 16 + quad * 4 + r;
                out[(size_t)gmm * 1024 + gn] = acc[mi][ni][r] + bi;
            }
        }
}

// ---------------------------------------------------------------------------
extern "C" void kernel_launch(void* const* d_in, const int* in_sizes, int n_in,
                              void* d_out, int out_size, void* d_ws, size_t ws_size,
                              hipStream_t stream) {
    const float* x     = (const float*)d_in[0];
    const float* W_qkv = (const float*)d_in[1];
    const float* b_qkv = (const float*)d_in[2];
    const float* W_out = (const float*)d_in[3];
    const float* b_out = (const float*)d_in[4];
    float* out = (float*)d_out;

    char* ws = (char*)d_ws;                            // 48 MB total footprint
    unsigned short* xb    = (unsigned short*)(ws);                      // 8 MB
    unsigned short* wqkvT = (unsigned short*)(ws + (size_t)( 8 << 20)); // 6 MB
    unsigned short* woutT = (unsigned short*)(ws + (size_t)(14 << 20)); // 2 MB
    unsigned short* Qb    = (unsigned short*)(ws + (size_t)(16 << 20)); // 8 MB
    unsigned short* Kb    = (unsigned short*)(ws + (size_t)(24 << 20)); // 8 MB
    unsigned short* Vtb   = (unsigned short*)(ws + (size_t)(32 << 20)); // 8 MB
    unsigned short* attnb = (unsigned short*)(ws + (size_t)(40 << 20)); // 8 MB
    // region reuse (stream-ordered):
    unsigned short* Vb    = attnb;                      // dead once attn writes P0 there
    unsigned short* P0    = attnb;
    unsigned short* P1    = xb;                         // xb dead after qkv_gemm
    float*          Lpart = (float*)(ws + (size_t)(8 << 20)); // wqkvT dead after qkv_gemm

    cast_x_kernel<<<4096, 256, 0, stream>>>(x, xb);
    transpose_cast_kernel<<<dim3(96, 32), 256, 0, stream>>>(W_qkv, wqkvT, 1024, 3072);
    transpose_cast_kernel<<<dim3(32, 32), 256, 0, stream>>>(W_out, woutT, 1024, 1024);
    qkv_gemm_kernel<<<dim3(24, 64), 256, 0, stream>>>(xb, wqkvT, b_qkv, Qb, Kb, Vb);
    vtrans_kernel<<<dim3(32, 32), 256, 0, stream>>>(Vb, Vtb);
    attn_kernel<<<dim3(16, 32, 2), 256, 0, stream>>>(Qb, Kb, Vtb, P0, P1, Lpart);
    out_gemm_kernel<<<dim3(16, 64), 256, 0, stream>>>(P0, P1, Lpart, woutT, b_out, out);
}

// Round 8
// 223.578 us; speedup vs baseline: 1.0450x; 1.0450x over previous
//
#include <hip/hip_runtime.h>

// ---------------------------------------------------------------------------
// MultiHeadAttention: B=2, T=2048, C=1024, H=16, D=64
// cast x -> bf16 ; transpose W_qkv, W_out -> bf16 [N][K] ;
// QKV GEMM (glds dbuf, 128x128) -> Q (prescaled 0.125*log2e), K [b,h,t,d],
// V^T [b,h,d,t] scattered in epilogue ; flash attention SPLIT-K x2
// (fixed-base softmax), Q in regs, K/V glds dbuf XOR-swizzled LDS with
// PRECOMPUTED base pointers (all swizzle XORs are loop-invariant: r&7==ln&7)
// + compile-time parity (kt unrolled x2) -> ds_read offset immediates ;
// combine ; out GEMM (glds dbuf, 128x128) + bias -> fp32.
// ---------------------------------------------------------------------------

typedef float  f32x4  __attribute__((ext_vector_type(4)));
typedef __bf16 bf16x8 __attribute__((ext_vector_type(8)));
typedef __bf16 bf16x4 __attribute__((ext_vector_type(4)));
typedef short  s16x4  __attribute__((ext_vector_type(4)));

#define QSCALE 0.18033688011112042f   // 0.125 * log2(e)

static __device__ __forceinline__ f32x4 mfma32(bf16x8 a, bf16x8 b, f32x4 c) {
    return __builtin_amdgcn_mfma_f32_16x16x32_bf16(a, b, c, 0, 0, 0);
}

static __device__ __forceinline__ f32x4 mfma16(bf16x4 a, bf16x4 b, f32x4 c) {
#if __has_builtin(__builtin_amdgcn_mfma_f32_16x16x16bf16_1k)
    return __builtin_amdgcn_mfma_f32_16x16x16bf16_1k(
        __builtin_bit_cast(s16x4, a), __builtin_bit_cast(s16x4, b), c, 0, 0, 0);
#else
    bf16x8 a8, b8;
    a8[0] = a[0]; a8[1] = a[1]; a8[2] = a[2]; a8[3] = a[3];
    a8[4] = a[0]; a8[5] = a[1]; a8[6] = a[2]; a8[7] = a[3];
    b8[0] = b[0]; b8[1] = b[1]; b8[2] = b[2]; b8[3] = b[3];
    b8[4] = __bf16(0.0f); b8[5] = __bf16(0.0f);
    b8[6] = __bf16(0.0f); b8[7] = __bf16(0.0f);
    return __builtin_amdgcn_mfma_f32_16x16x32_bf16(a8, b8, c, 0, 0, 0);
#endif
}

static __device__ __forceinline__ bf16x8 ld8(const unsigned short* p) {
    return __builtin_bit_cast(bf16x8, *(const uint4*)p);
}
static __device__ __forceinline__ bf16x4 ld4(const unsigned short* p) {
    return __builtin_bit_cast(bf16x4, *(const uint2*)p);
}
static __device__ __forceinline__ unsigned short bfbits(float f) {
    __bf16 h = (__bf16)f;
    return __builtin_bit_cast(unsigned short, h);
}
static __device__ __forceinline__ float bf2f(unsigned short u) {
    unsigned int v = ((unsigned int)u) << 16;
    return __builtin_bit_cast(float, v);
}

static __device__ __forceinline__ void glds16(const unsigned short* g,
                                              unsigned short* lds_base) {
    __builtin_amdgcn_global_load_lds(
        (const __attribute__((address_space(1))) unsigned int*)g,
        (__attribute__((address_space(3))) unsigned int*)lds_base, 16, 0, 0);
}

// ---------------------------------------------------------------- cast x
__global__ __launch_bounds__(256) void cast_x_kernel(
    const float* __restrict__ x, unsigned short* __restrict__ xb) {
    int i = blockIdx.x * 256 + threadIdx.x;
    float4 v = ((const float4*)x)[i];
    ushort4 o;
    o.x = bfbits(v.x); o.y = bfbits(v.y); o.z = bfbits(v.z); o.w = bfbits(v.w);
    ((ushort4*)xb)[i] = o;
}

// ------------------------------------------------- transpose + cast weights
__global__ __launch_bounds__(256) void transpose_cast_kernel(
    const float* __restrict__ W, unsigned short* __restrict__ Wt, int K, int N) {
    __shared__ float tile[32][33];
    int tx = threadIdx.x & 31, ty = threadIdx.x >> 5;
    int n0 = blockIdx.x * 32, k0 = blockIdx.y * 32;
#pragma unroll
    for (int i = 0; i < 4; i++) {
        int r = ty + i * 8;
        tile[r][tx] = W[(size_t)(k0 + r) * N + n0 + tx];
    }
    __syncthreads();
#pragma unroll
    for (int i = 0; i < 4; i++) {
        int r = ty + i * 8;
        Wt[(size_t)(n0 + r) * K + k0 + tx] = bfbits(tile[tx][r]);
    }
}

// ---------------------------------------------------------------- QKV GEMM
// R5 config: 128x128 tile, glds dbuf, V^T scattered in epilogue.
__global__ __launch_bounds__(256) void qkv_gemm_kernel(
    const unsigned short* __restrict__ A, const unsigned short* __restrict__ Bt,
    const float* __restrict__ bias, unsigned short* __restrict__ Qb,
    unsigned short* __restrict__ Kb, unsigned short* __restrict__ Vtb) {
    __shared__ unsigned short As[2][128 * 32];
    __shared__ unsigned short Bs[2][128 * 32];
    const int tid = threadIdx.x;
    const int lane = tid & 63, w = tid >> 6;
    const int ln = lane & 15, quad = lane >> 4;
    const int wm = (w >> 1) * 64, wn = (w & 1) * 64;
    const int m0 = blockIdx.y * 128, n0 = blockIdx.x * 128;
    const int sr = lane >> 2, sc = (lane & 3) * 8;
    f32x4 acc[4][4] = {};
#pragma unroll
    for (int i = 0; i < 2; i++) {
        int r0 = w * 32 + i * 16;
        glds16(&A[(size_t)(m0 + r0 + sr) * 1024 + sc], &As[0][r0 * 32]);
        glds16(&Bt[(size_t)(n0 + r0 + sr) * 1024 + sc], &Bs[0][r0 * 32]);
    }
    __syncthreads();
    for (int kt = 0; kt < 32; kt++) {
        const int cur = kt & 1;
        if (kt + 1 < 32) {
            const int nxt = cur ^ 1;
            const int kc = (kt + 1) * 32;
#pragma unroll
            for (int i = 0; i < 2; i++) {
                int r0 = w * 32 + i * 16;
                glds16(&A[(size_t)(m0 + r0 + sr) * 1024 + kc + sc], &As[nxt][r0 * 32]);
                glds16(&Bt[(size_t)(n0 + r0 + sr) * 1024 + kc + sc], &Bs[nxt][r0 * 32]);
            }
        }
        bf16x8 af[4], bf[4];
#pragma unroll
        for (int mi = 0; mi < 4; mi++)
            af[mi] = ld8(&As[cur][(wm + mi * 16 + ln) * 32 + quad * 8]);
#pragma unroll
        for (int ni = 0; ni < 4; ni++)
            bf[ni] = ld8(&Bs[cur][(wn + ni * 16 + ln) * 32 + quad * 8]);
#pragma unroll
        for (int mi = 0; mi < 4; mi++)
#pragma unroll
            for (int ni = 0; ni < 4; ni++)
                acc[mi][ni] = mfma32(af[mi], bf[ni], acc[mi][ni]);
        __syncthreads();
    }
#pragma unroll
    for (int mi = 0; mi < 4; mi++)
#pragma unroll
        for (int ni = 0; ni < 4; ni++) {
            int gn = n0 + wn + ni * 16 + ln;
            float bi = bias[gn];
            int h = gn / 192, rr = gn - h * 192;
#pragma unroll
            for (int r = 0; r < 4; r++) {
                int gm = m0 + wm + mi * 16 + quad * 4 + r;
                float v = acc[mi][ni][r] + bi;
                int b = gm >> 11, t = gm & 2047;
                size_t base = ((size_t)(b * 16 + h) * 2048 + t) * 64;
                if (rr < 64)        Qb[base + rr] = bfbits(v * QSCALE);
                else if (rr < 128)  Kb[base + rr - 64] = bfbits(v);
                else Vtb[((size_t)(b * 16 + h) * 64 + (rr - 128)) * 2048 + t] = bfbits(v);
            }
        }
}

// ---------------------------------------------------------------- attention
// Split-K x2; Q in regs; K/V glds dbuf XOR-swizzled. All LDS read/stage
// addresses precomputed (swizzle XOR loop-invariant); kt unrolled x2 so
// buffer parity folds into ds_read offset immediates.
__global__ __launch_bounds__(256, 4) void attn_kernel(
    const unsigned short* __restrict__ Q, const unsigned short* __restrict__ K,
    const unsigned short* __restrict__ Vt, unsigned short* __restrict__ Op0,
    unsigned short* __restrict__ Op1, float* __restrict__ Lpart) {
    __shared__ unsigned short Ks[2][64 * 64];
    __shared__ unsigned short Vs[2][64 * 64];
    const int bh = blockIdx.y, qt = blockIdx.x, ks = blockIdx.z;
    const unsigned short* Qg = Q + ((size_t)bh * 2048 + qt * 128) * 64;
    const unsigned short* Kg = K + ((size_t)bh * 2048 + ks * 1024) * 64;
    const unsigned short* Vg = Vt + (size_t)bh * 64 * 2048 + ks * 1024;
    const int tid = threadIdx.x;
    const int lane = tid & 63, w = tid >> 6;
    const int ln = lane & 15, quad = lane >> 4;
    const int lr = lane >> 3, lg = lane & 7;
    const int e = ln & 7;

    // Q fragments (B-operand: n=q=ln, k=d)
    bf16x8 qf[2][2];
#pragma unroll
    for (int h = 0; h < 2; h++) {
        const unsigned short* qp = Qg + (size_t)(w * 32 + h * 16 + ln) * 64;
        qf[h][0] = ld8(qp + quad * 8);
        qf[h][1] = ld8(qp + 32 + quad * 8);
    }

    // ---- loop-invariant LDS compute-read bases (elements; +ms*1024/+df*1024
    // and +parity*4096 are constant offsets -> ds_read immediates)
    const unsigned short* kb0 = &Ks[0][ln * 64 + (quad ^ e) * 8];
    const unsigned short* kb1 = &Ks[0][ln * 64 + ((4 + quad) ^ e) * 8];
    const unsigned short* vb0 = &Vs[0][ln * 64 + (((quad >> 1)) ^ e) * 8 + (quad & 1) * 4];
    const unsigned short* vb1 = &Vs[0][ln * 64 + ((2 + (quad >> 1)) ^ e) * 8 + (quad & 1) * 4];
    const unsigned short* vb2 = &Vs[0][ln * 64 + ((4 + (quad >> 1)) ^ e) * 8 + (quad & 1) * 4];
    const unsigned short* vb3 = &Vs[0][ln * 64 + ((6 + (quad >> 1)) ^ e) * 8 + (quad & 1) * 4];
    const unsigned short* vbms[4] = {vb0, vb1, vb2, vb3};

    // ---- loop-invariant staging offsets (g = lg^lr is lane-constant)
    const int kof0 = (w * 16 + lr) * 64 + (lg ^ lr) * 8;
    const int kof1 = (w * 16 + 8 + lr) * 64 + (lg ^ lr) * 8;
    const int vof0 = (w * 16 + lr) * 2048 + (lg ^ lr) * 8;
    const int vof1 = (w * 16 + 8 + lr) * 2048 + (lg ^ lr) * 8;
    unsigned short* kd0[2] = {&Ks[0][(w * 16) * 64], &Ks[1][(w * 16) * 64]};
    unsigned short* kd1[2] = {&Ks[0][(w * 16 + 8) * 64], &Ks[1][(w * 16 + 8) * 64]};
    unsigned short* vd0[2] = {&Vs[0][(w * 16) * 64], &Vs[1][(w * 16) * 64]};
    unsigned short* vd1[2] = {&Vs[0][(w * 16 + 8) * 64], &Vs[1][(w * 16 + 8) * 64]};

    // stage tile 0
    glds16(Kg + kof0, kd0[0]);
    glds16(Kg + kof1, kd1[0]);
    glds16(Vg + vof0, vd0[0]);
    glds16(Vg + vof1, vd1[0]);
    __syncthreads();

    const unsigned short* KgR = Kg + 4096;   // next K tile (64 rows x 64)
    const unsigned short* VgR = Vg + 64;     // next V tile (64 t-cols)

    bf16x4 ones;
    ones[0] = __bf16(1.0f); ones[1] = __bf16(1.0f);
    ones[2] = __bf16(1.0f); ones[3] = __bf16(1.0f);
    f32x4 o[2][4] = {};
    f32x4 lacc[2] = {};

#define ATTN_TILE(CUR, PREF)                                                  \
    do {                                                                      \
        if (PREF) {                                                           \
            glds16(KgR + kof0, kd0[CUR ^ 1]);                                 \
            glds16(KgR + kof1, kd1[CUR ^ 1]);                                 \
            glds16(VgR + vof0, vd0[CUR ^ 1]);                                 \
            glds16(VgR + vof1, vd1[CUR ^ 1]);                                 \
            KgR += 4096; VgR += 64;                                           \
        }                                                                     \
        f32x4 s[2][4] = {};                                                   \
        _Pragma("unroll")                                                     \
        for (int ms = 0; ms < 4; ms++) {                                      \
            bf16x8 a0 = ld8(kb0 + (CUR) * 4096 + ms * 1024);                  \
            bf16x8 a1 = ld8(kb1 + (CUR) * 4096 + ms * 1024);                  \
            _Pragma("unroll")                                                 \
            for (int h = 0; h < 2; h++) {                                     \
                s[h][ms] = mfma32(a0, qf[h][0], s[h][ms]);                    \
                s[h][ms] = mfma32(a1, qf[h][1], s[h][ms]);                    \
            }                                                                 \
        }                                                                     \
        bf16x4 pb[2][4];                                                      \
        _Pragma("unroll")                                                     \
        for (int h = 0; h < 2; h++)                                           \
            _Pragma("unroll")                                                 \
            for (int ms = 0; ms < 4; ms++) {                                  \
                f32x4 pv;                                                     \
                pv[0] = exp2f(s[h][ms][0]); pv[1] = exp2f(s[h][ms][1]);       \
                pv[2] = exp2f(s[h][ms][2]); pv[3] = exp2f(s[h][ms][3]);       \
                pb[h][ms] = __builtin_convertvector(pv, bf16x4);              \
            }                                                                 \
        _Pragma("unroll")                                                     \
        for (int h = 0; h < 2; h++)                                           \
            _Pragma("unroll")                                                 \
            for (int ms = 0; ms < 4; ms++)                                    \
                lacc[h] = mfma16(ones, pb[h][ms], lacc[h]);                   \
        _Pragma("unroll")                                                     \
        for (int df = 0; df < 4; df++)                                        \
            _Pragma("unroll")                                                 \
            for (int ms = 0; ms < 4; ms++) {                                  \
                bf16x4 a = ld4(vbms[ms] + (CUR) * 4096 + df * 1024);          \
                o[0][df] = mfma16(a, pb[0][ms], o[0][df]);                    \
                o[1][df] = mfma16(a, pb[1][ms], o[1][df]);                    \
            }                                                                 \
        __syncthreads();                                                      \
    } while (0)

    for (int it = 0; it < 8; it++) {
        ATTN_TILE(0, true);                 // tile 2*it, prefetch 2*it+1
        ATTN_TILE(1, (it < 7));             // tile 2*it+1, prefetch 2*it+2
    }
#undef ATTN_TILE

    const int b = bh >> 4, hh = bh & 15;
    unsigned short* Ob = ks ? Op1 : Op0;
#pragma unroll
    for (int h = 0; h < 2; h++) {
        int qrow = qt * 128 + w * 32 + h * 16 + ln;
        if (quad == 0)
            Lpart[(size_t)ks * 65536 + bh * 2048 + qrow] = lacc[h][0];
        size_t row = ((size_t)b * 2048 + qrow) * 1024 + hh * 64;
#pragma unroll
        for (int df = 0; df < 4; df++) {
            ushort4 pk;
            pk.x = bfbits(o[h][df][0]); pk.y = bfbits(o[h][df][1]);
            pk.z = bfbits(o[h][df][2]); pk.w = bfbits(o[h][df][3]);
            *(ushort4*)&Ob[row + df * 16 + quad * 4] = pk;
        }
    }
}

// ---------------------------------------------------------------- combine
__global__ __launch_bounds__(256) void combine_kernel(
    const unsigned short* __restrict__ P0, const unsigned short* __restrict__ P1,
    const float* __restrict__ L, unsigned short* __restrict__ outp) {
    int i = blockIdx.x * 256 + threadIdx.x;
    int e = i << 2;
    int row = e >> 10;
    int hh = (e >> 6) & 15;
    int b = row >> 11, t = row & 2047;
    int bh = b * 16 + hh;
    float inv = 1.0f / (L[bh * 2048 + t] + L[65536 + bh * 2048 + t]);
    ushort4 a = ((const ushort4*)P0)[i];
    ushort4 c = ((const ushort4*)P1)[i];
    ushort4 o;
    o.x = bfbits((bf2f(a.x) + bf2f(c.x)) * inv);
    o.y = bfbits((bf2f(a.y) + bf2f(c.y)) * inv);
    o.z = bfbits((bf2f(a.z) + bf2f(c.z)) * inv);
    o.w = bfbits((bf2f(a.w) + bf2f(c.w)) * inv);
    ((ushort4*)outp)[i] = o;
}

// ---------------------------------------------------------------- out GEMM
__global__ __launch_bounds__(256) void out_gemm_kernel(
    const unsigned short* __restrict__ A, const unsigned short* __restrict__ Bt,
    const float* __restrict__ bias, float* __restrict__ out) {
    __shared__ unsigned short As[2][128 * 32];
    __shared__ unsigned short Bs[2][128 * 32];
    const int tid = threadIdx.x;
    const int lane = tid & 63, w = tid >> 6;
    const int ln = lane & 15, quad = lane >> 4;
    const int wm = (w >> 1) * 64, wn = (w & 1) * 64;
    const int m0 = blockIdx.y * 128, n0 = blockIdx.x * 128;
    const int sr = lane >> 2, sc = (lane & 3) * 8;
    f32x4 acc[4][4] = {};
#pragma unroll
    for (int i = 0; i < 2; i++) {
        int r0 = w * 32 + i * 16;
        glds16(&A[(size_t)(m0 + r0 + sr) * 1024 + sc], &As[0][r0 * 32]);
        glds16(&Bt[(size_t)(n0 + r0 + sr) * 1024 + sc], &Bs[0][r0 * 32]);
    }
    __syncthreads();
    for (int kt = 0; kt < 32; kt++) {
        const int cur = kt & 1;
        if (kt + 1 < 32) {
            const int nxt = cur ^ 1;
            const int kc = (kt + 1) * 32;
#pragma unroll
            for (int i = 0; i < 2; i++) {
                int r0 = w * 32 + i * 16;
                glds16(&A[(size_t)(m0 + r0 + sr) * 1024 + kc + sc], &As[nxt][r0 * 32]);
                glds16(&Bt[(size_t)(n0 + r0 + sr) * 1024 + kc + sc], &Bs[nxt][r0 * 32]);
            }
        }
        bf16x8 af[4], bf[4];
#pragma unroll
        for (int mi = 0; mi < 4; mi++)
            af[mi] = ld8(&As[cur][(wm + mi * 16 + ln) * 32 + quad * 8]);
#pragma unroll
        for (int ni = 0; ni < 4; ni++)
            bf[ni] = ld8(&Bs[cur][(wn + ni * 16 + ln) * 32 + quad * 8]);
#pragma unroll
        for (int mi = 0; mi < 4; mi++)
#pragma unroll
            for (int ni = 0; ni < 4; ni++)
                acc[mi][ni] = mfma32(af[mi], bf[ni], acc[mi][ni]);
        __syncthreads();
    }
#pragma unroll
    for (int mi = 0; mi < 4; mi++)
#pragma unroll
        for (int ni = 0; ni < 4; ni++) {
            int gn = n0 + wn + ni * 16 + ln;
            float bi = bias[gn];
#pragma unroll
            for (int r = 0; r < 4; r++) {
                int gm = m0 + wm + mi * 16 + quad * 4 + r;
                out[(size_t)gm * 1024 + gn] = acc[mi][ni][r] + bi;
            }
        }
}

// ---------------------------------------------------------------------------
extern "C" void kernel_launch(void* const* d_in, const int* in_sizes, int n_in,
                              void* d_out, int out_size, void* d_ws, size_t ws_size,
                              hipStream_t stream) {
    const float* x     = (const float*)d_in[0];
    const float* W_qkv = (const float*)d_in[1];
    const float* b_qkv = (const float*)d_in[2];
    const float* W_out = (const float*)d_in[3];
    const float* b_out = (const float*)d_in[4];
    float* out = (float*)d_out;

    char* ws = (char*)d_ws;                            // 48 MB total footprint
    unsigned short* xb    = (unsigned short*)(ws);                      // 8 MB
    unsigned short* wqkvT = (unsigned short*)(ws + (size_t)( 8 << 20)); // 6 MB
    unsigned short* woutT = (unsigned short*)(ws + (size_t)(14 << 20)); // 2 MB
    unsigned short* Qb    = (unsigned short*)(ws + (size_t)(16 << 20)); // 8 MB
    unsigned short* Kb    = (unsigned short*)(ws + (size_t)(24 << 20)); // 8 MB
    unsigned short* Vtb   = (unsigned short*)(ws + (size_t)(32 << 20)); // 8 MB
    unsigned short* attnb = (unsigned short*)(ws + (size_t)(40 << 20)); // 8 MB
    // region reuse (stream-ordered):
    unsigned short* P1    = xb;                         // xb dead after qkv_gemm
    float*          Lpart = (float*)(ws + (size_t)(8 << 20)); // wqkvT dead after qkv_gemm

    cast_x_kernel<<<4096, 256, 0, stream>>>(x, xb);
    transpose_cast_kernel<<<dim3(96, 32), 256, 0, stream>>>(W_qkv, wqkvT, 1024, 3072);
    transpose_cast_kernel<<<dim3(32, 32), 256, 0, stream>>>(W_out, woutT, 1024, 1024);
    qkv_gemm_kernel<<<dim3(24, 32), 256, 0, stream>>>(xb, wqkvT, b_qkv, Qb, Kb, Vtb);
    attn_kernel<<<dim3(16, 32, 2), 256, 0, stream>>>(Qb, Kb, Vtb, attnb, P1, Lpart);
    combine_kernel<<<4096, 256, 0, stream>>>(attnb, P1, Lpart, attnb);
    out_gemm_kernel<<<dim3(8, 32), 256, 0, stream>>>(attnb, woutT, b_out, out);
}